// Round 1
// baseline (867.933 us; speedup 1.0000x reference)
//
#include <hip/hip_runtime.h>
#include <hip/hip_bf16.h>
#include <stdint.h>

#define M_DIM 8192
#define N_DIM 4096
#define K_DIM 4096
#define R_DIM 32
#define KPAD  4160   // 4096 quant cols + 32 lora cols + 32 zero pad = 65 * 64
#define QMAXF 7.0f

using bf16_t = __hip_bfloat16;
typedef __attribute__((ext_vector_type(4))) float f32x4;
typedef __attribute__((ext_vector_type(8))) short bf16x8;

// ---------------------------------------------------------------------------
// async global->LDS 16B stage (per-lane dest must be uniform_base + lane*16)
// ---------------------------------------------------------------------------
__device__ __forceinline__ void stage16(const void* g, void* l) {
#if defined(__has_builtin) && __has_builtin(__builtin_amdgcn_global_load_lds)
  __builtin_amdgcn_global_load_lds(
      (const __attribute__((address_space(1))) unsigned int*)g,
      (__attribute__((address_space(3))) unsigned int*)l, 16, 0, 0);
#else
  *(uint4*)l = *(const uint4*)g;
#endif
}

// ---------------------------------------------------------------------------
// Quantize x (with smooth) -> bf16 into Ap[M][KPAD] cols 0..4095; zero pad
// cols 4128..4159. Cols 4096..4127 (t = xs@lora_down) written by lora kernel.
// ---------------------------------------------------------------------------
__global__ __launch_bounds__(256) void quant_x_kernel(
    const float* __restrict__ x, const float* __restrict__ smooth,
    bf16_t* __restrict__ Ap) {
  const int row = blockIdx.x;
  const int tid = threadIdx.x;
  const int k0  = tid * 16;                 // 16 elems/thread, group64 = 4 threads
  const float* xr = x + (size_t)row * K_DIM + k0;
  const float* sr = smooth + k0;

  float v[16];
#pragma unroll
  for (int i = 0; i < 4; ++i) {
    float4 xv = *(const float4*)(xr + i * 4);
    float4 sv = *(const float4*)(sr + i * 4);
    v[i*4+0] = xv.x * sv.x; v[i*4+1] = xv.y * sv.y;
    v[i*4+2] = xv.z * sv.z; v[i*4+3] = xv.w * sv.w;
  }
  float am = 0.f;
#pragma unroll
  for (int i = 0; i < 16; ++i) am = fmaxf(am, fabsf(v[i]));
  am = fmaxf(am, __shfl_xor(am, 1));
  am = fmaxf(am, __shfl_xor(am, 2));
  const float scale = fmaxf(am / QMAXF, 1e-8f);

  alignas(16) bf16_t o[16];
#pragma unroll
  for (int i = 0; i < 16; ++i) {
    float q = rintf(v[i] / scale);          // IEEE div + round-half-even = jnp
    q = fminf(fmaxf(q, -8.f), 7.f);
    o[i] = __float2bfloat16(q * scale);
  }
  bf16_t* dst = Ap + (size_t)row * KPAD + k0;
  ((uint4*)dst)[0] = ((uint4*)o)[0];
  ((uint4*)dst)[1] = ((uint4*)o)[1];

  if (tid < 32) Ap[(size_t)row * KPAD + 4128 + tid] = __float2bfloat16(0.f);
}

// ---------------------------------------------------------------------------
// Quantize w_res -> bf16 into Bp[N][KPAD] cols 0..4095; lora_up into cols
// 4096..4127; zeros into 4128..4159.
// ---------------------------------------------------------------------------
__global__ __launch_bounds__(256) void quant_w_kernel(
    const float* __restrict__ w, const float* __restrict__ lora_up,
    bf16_t* __restrict__ Bp) {
  const int row = blockIdx.x;
  const int tid = threadIdx.x;
  const int k0  = tid * 16;
  const float* wr = w + (size_t)row * K_DIM + k0;

  float v[16];
#pragma unroll
  for (int i = 0; i < 4; ++i) {
    float4 wv = *(const float4*)(wr + i * 4);
    v[i*4+0] = wv.x; v[i*4+1] = wv.y; v[i*4+2] = wv.z; v[i*4+3] = wv.w;
  }
  float am = 0.f;
#pragma unroll
  for (int i = 0; i < 16; ++i) am = fmaxf(am, fabsf(v[i]));
  am = fmaxf(am, __shfl_xor(am, 1));
  am = fmaxf(am, __shfl_xor(am, 2));
  const float scale = fmaxf(am / QMAXF, 1e-8f);

  alignas(16) bf16_t o[16];
#pragma unroll
  for (int i = 0; i < 16; ++i) {
    float q = rintf(v[i] / scale);
    q = fminf(fmaxf(q, -8.f), 7.f);
    o[i] = __float2bfloat16(q * scale);
  }
  bf16_t* dst = Bp + (size_t)row * KPAD + k0;
  ((uint4*)dst)[0] = ((uint4*)o)[0];
  ((uint4*)dst)[1] = ((uint4*)o)[1];

  if (tid < 32) {
    Bp[(size_t)row * KPAD + 4096 + tid] = __float2bfloat16(lora_up[row * R_DIM + tid]);
  } else if (tid < 64) {
    Bp[(size_t)row * KPAD + 4096 + tid] = __float2bfloat16(0.f);
  }
}

// ---------------------------------------------------------------------------
// t = (x*smooth) @ lora_down  [M x 32], written bf16 into Ap cols 4096..4127.
// Block = 64 rows of M; 256 threads; thread owns (rowgrp = tid>>5 -> 8 rows,
// r = tid&31).
// ---------------------------------------------------------------------------
__global__ __launch_bounds__(256) void lora_down_kernel(
    const float* __restrict__ x, const float* __restrict__ smooth,
    const float* __restrict__ ld, bf16_t* __restrict__ Ap) {
  __shared__ float xs[64][65];   // +1 pad
  __shared__ float lt[64][32];

  const int tid = threadIdx.x;
  const int rowbase = (tid >> 5) * 8;
  const int r = tid & 31;
  const int m0 = blockIdx.x * 64;
  const int srow = tid >> 2;            // 0..63
  const int scol = (tid & 3) * 16;      // x stage cols
  const int lcol = (tid & 3) * 8;       // ld stage cols

  float acc[8] = {0.f,0.f,0.f,0.f,0.f,0.f,0.f,0.f};

  for (int kk = 0; kk < K_DIM; kk += 64) {
    // stage xs tile 64x64 (x * smooth)
#pragma unroll
    for (int i = 0; i < 4; ++i) {
      float4 xv = *(const float4*)(x + (size_t)(m0 + srow) * K_DIM + kk + scol + i * 4);
      float4 sv = *(const float4*)(smooth + kk + scol + i * 4);
      xs[srow][scol + i*4 + 0] = xv.x * sv.x;
      xs[srow][scol + i*4 + 1] = xv.y * sv.y;
      xs[srow][scol + i*4 + 2] = xv.z * sv.z;
      xs[srow][scol + i*4 + 3] = xv.w * sv.w;
    }
    // stage lora_down tile 64x32
    {
      float4 a = *(const float4*)(ld + (size_t)(kk + srow) * R_DIM + lcol);
      float4 b = *(const float4*)(ld + (size_t)(kk + srow) * R_DIM + lcol + 4);
      lt[srow][lcol + 0] = a.x; lt[srow][lcol + 1] = a.y;
      lt[srow][lcol + 2] = a.z; lt[srow][lcol + 3] = a.w;
      lt[srow][lcol + 4] = b.x; lt[srow][lcol + 5] = b.y;
      lt[srow][lcol + 6] = b.z; lt[srow][lcol + 7] = b.w;
    }
    __syncthreads();
#pragma unroll 8
    for (int k = 0; k < 64; ++k) {
      float lv = lt[k][r];
#pragma unroll
      for (int i = 0; i < 8; ++i) acc[i] += xs[rowbase + i][k] * lv;
    }
    __syncthreads();
  }
#pragma unroll
  for (int i = 0; i < 8; ++i)
    Ap[(size_t)(m0 + rowbase + i) * KPAD + 4096 + r] = __float2bfloat16(acc[i]);
}

// ---------------------------------------------------------------------------
// C[M][N] = Ap[M][KPAD] @ Bp[N][KPAD]^T + bias.  m97-structure:
// 128x128 tile, BK=64, 4 waves (2x2), 4x4 16x16x32 frags/wave,
// global_load_lds width-16 staging, XCD-swizzled 1D grid.
// ---------------------------------------------------------------------------
#define BM 128
#define BN 128
#define BK 64

__global__ __launch_bounds__(256) void gemm_kernel(
    const bf16_t* __restrict__ A, const bf16_t* __restrict__ B,
    const float* __restrict__ bias, float* __restrict__ C) {
  // XCD-aware swizzle: nwg = 2048, divisible by 8
  const int nwg = (M_DIM / BM) * (N_DIM / BN);
  const int cpx = nwg >> 3;
  const int wg  = blockIdx.x;
  const int swz = (wg & 7) * cpx + (wg >> 3);
  const int bn  = swz & (N_DIM / BN - 1);   // 0..31
  const int bm  = swz >> 5;                 // 0..63

  __shared__ bf16_t As[BM][BK];   // 16 KiB
  __shared__ bf16_t Bs[BN][BK];   // 16 KiB

  const int tid  = threadIdx.x;
  const int lane = tid & 63;
  const int wid  = tid >> 6;      // 0..3
  const int wm   = wid >> 1;      // 0..1
  const int wn   = wid & 1;       // 0..1

  f32x4 acc[4][4] = {};

  // staging geometry: thread t stages 16B at LDS byte offset t*16 + j*4096
  const int srow = tid >> 3;            // 0..31
  const int scol = (tid & 7) * 8;       // elem col, 16B granules
  const bf16_t* Ag = A + ((size_t)(bm * BM + srow)) * KPAD + scol;
  const bf16_t* Bg = B + ((size_t)(bn * BN + srow)) * KPAD + scol;

  for (int kt = 0; kt < KPAD; kt += BK) {
#pragma unroll
    for (int j = 0; j < 4; ++j) {
      stage16(Ag + (size_t)(j * 32) * KPAD + kt, &As[srow + j * 32][scol]);
      stage16(Bg + (size_t)(j * 32) * KPAD + kt, &Bs[srow + j * 32][scol]);
    }
    __syncthreads();   // compiler drains vmcnt before s_barrier

#pragma unroll
    for (int ks = 0; ks < BK; ks += 32) {
      bf16x8 af[4], bfr[4];
      const int kfr = ks + (lane >> 4) * 8;
#pragma unroll
      for (int i = 0; i < 4; ++i) {
        af[i]  = *(const bf16x8*)&As[wm * 64 + i * 16 + (lane & 15)][kfr];
        bfr[i] = *(const bf16x8*)&Bs[wn * 64 + i * 16 + (lane & 15)][kfr];
      }
#pragma unroll
      for (int i = 0; i < 4; ++i)
#pragma unroll
        for (int j = 0; j < 4; ++j)
          acc[i][j] = __builtin_amdgcn_mfma_f32_16x16x32_bf16(af[i], bfr[j], acc[i][j], 0, 0, 0);
    }
    __syncthreads();
  }

  // epilogue: C/D layout col = lane&15, row = (lane>>4)*4 + reg
  const int coln = lane & 15;
  const int rowq = (lane >> 4) * 4;
#pragma unroll
  for (int j = 0; j < 4; ++j) {
    const int gc = bn * BN + wn * 64 + j * 16 + coln;
    const float bv = bias[gc];
#pragma unroll
    for (int i = 0; i < 4; ++i) {
      const int gr = bm * BM + wm * 64 + i * 16 + rowq;
#pragma unroll
      for (int q = 0; q < 4; ++q)
        C[(size_t)(gr + q) * N_DIM + gc] = acc[i][j][q] + bv;
    }
  }
}

// ---------------------------------------------------------------------------
extern "C" void kernel_launch(void* const* d_in, const int* in_sizes, int n_in,
                              void* d_out, int out_size, void* d_ws, size_t ws_size,
                              hipStream_t stream) {
  const float* x         = (const float*)d_in[0];
  const float* w_res     = (const float*)d_in[1];
  const float* lora_down = (const float*)d_in[2];
  const float* lora_up   = (const float*)d_in[3];
  const float* smooth    = (const float*)d_in[4];
  const float* b         = (const float*)d_in[5];
  float* out = (float*)d_out;

  // workspace: Ap [M][KPAD] bf16 (68.2 MB) then Bp [N][KPAD] bf16 (34.1 MB)
  bf16_t* Ap = (bf16_t*)d_ws;
  bf16_t* Bp = Ap + (size_t)M_DIM * KPAD;

  quant_x_kernel<<<M_DIM, 256, 0, stream>>>(x, smooth, Ap);
  quant_w_kernel<<<N_DIM, 256, 0, stream>>>(w_res, lora_up, Bp);
  lora_down_kernel<<<M_DIM / 64, 256, 0, stream>>>(x, smooth, lora_down, Ap);
  gemm_kernel<<<(M_DIM / BM) * (N_DIM / BN), 256, 0, stream>>>(Ap, Bp, b, out);
}

// Round 2
// 519.865 us; speedup vs baseline: 1.6695x; 1.6695x over previous
//
#include <hip/hip_runtime.h>
#include <hip/hip_bf16.h>
#include <stdint.h>

#define M_DIM 8192
#define N_DIM 4096
#define K_DIM 4096
#define R_DIM 32
#define KPAD  4160   // 4096 quant cols + 32 lora cols + 32 zero pad = 65 * 64
#define QMAXF 7.0f

using bf16_t = __hip_bfloat16;
typedef __attribute__((ext_vector_type(4))) float f32x4;
typedef __attribute__((ext_vector_type(8))) short bf16x8;

// ---------------------------------------------------------------------------
// async global->LDS 16B stage (LDS dest must be wave-uniform base + lane*16)
// ---------------------------------------------------------------------------
__device__ __forceinline__ void stage16(const void* g, void* l) {
#if defined(__has_builtin) && __has_builtin(__builtin_amdgcn_global_load_lds)
  __builtin_amdgcn_global_load_lds(
      (const __attribute__((address_space(1))) unsigned int*)g,
      (__attribute__((address_space(3))) unsigned int*)l, 16, 0, 0);
#else
  *(uint4*)l = *(const uint4*)g;
#endif
}

// ---------------------------------------------------------------------------
// Quantize x (with smooth) -> bf16 into Ap[M][KPAD] cols 0..4095; zero pad
// cols 4128..4159. Cols 4096..4127 (t = xs@lora_down) written by lora kernel.
// ---------------------------------------------------------------------------
__global__ __launch_bounds__(256) void quant_x_kernel(
    const float* __restrict__ x, const float* __restrict__ smooth,
    bf16_t* __restrict__ Ap) {
  const int row = blockIdx.x;
  const int tid = threadIdx.x;
  const int k0  = tid * 16;                 // 16 elems/thread, group64 = 4 threads
  const float* xr = x + (size_t)row * K_DIM + k0;
  const float* sr = smooth + k0;

  float v[16];
#pragma unroll
  for (int i = 0; i < 4; ++i) {
    float4 xv = *(const float4*)(xr + i * 4);
    float4 sv = *(const float4*)(sr + i * 4);
    v[i*4+0] = xv.x * sv.x; v[i*4+1] = xv.y * sv.y;
    v[i*4+2] = xv.z * sv.z; v[i*4+3] = xv.w * sv.w;
  }
  float am = 0.f;
#pragma unroll
  for (int i = 0; i < 16; ++i) am = fmaxf(am, fabsf(v[i]));
  am = fmaxf(am, __shfl_xor(am, 1));
  am = fmaxf(am, __shfl_xor(am, 2));
  const float scale = fmaxf(am / QMAXF, 1e-8f);

  alignas(16) bf16_t o[16];
#pragma unroll
  for (int i = 0; i < 16; ++i) {
    float q = rintf(v[i] / scale);          // IEEE div + round-half-even = jnp
    q = fminf(fmaxf(q, -8.f), 7.f);
    o[i] = __float2bfloat16(q * scale);
  }
  bf16_t* dst = Ap + (size_t)row * KPAD + k0;
  ((uint4*)dst)[0] = ((uint4*)o)[0];
  ((uint4*)dst)[1] = ((uint4*)o)[1];

  if (tid < 32) Ap[(size_t)row * KPAD + 4128 + tid] = __float2bfloat16(0.f);
}

// ---------------------------------------------------------------------------
// Quantize w_res -> bf16 into Bp[N][KPAD] cols 0..4095; lora_up into cols
// 4096..4127; zeros into 4128..4159.
// ---------------------------------------------------------------------------
__global__ __launch_bounds__(256) void quant_w_kernel(
    const float* __restrict__ w, const float* __restrict__ lora_up,
    bf16_t* __restrict__ Bp) {
  const int row = blockIdx.x;
  const int tid = threadIdx.x;
  const int k0  = tid * 16;
  const float* wr = w + (size_t)row * K_DIM + k0;

  float v[16];
#pragma unroll
  for (int i = 0; i < 4; ++i) {
    float4 wv = *(const float4*)(wr + i * 4);
    v[i*4+0] = wv.x; v[i*4+1] = wv.y; v[i*4+2] = wv.z; v[i*4+3] = wv.w;
  }
  float am = 0.f;
#pragma unroll
  for (int i = 0; i < 16; ++i) am = fmaxf(am, fabsf(v[i]));
  am = fmaxf(am, __shfl_xor(am, 1));
  am = fmaxf(am, __shfl_xor(am, 2));
  const float scale = fmaxf(am / QMAXF, 1e-8f);

  alignas(16) bf16_t o[16];
#pragma unroll
  for (int i = 0; i < 16; ++i) {
    float q = rintf(v[i] / scale);
    q = fminf(fmaxf(q, -8.f), 7.f);
    o[i] = __float2bfloat16(q * scale);
  }
  bf16_t* dst = Bp + (size_t)row * KPAD + k0;
  ((uint4*)dst)[0] = ((uint4*)o)[0];
  ((uint4*)dst)[1] = ((uint4*)o)[1];

  if (tid < 32) {
    Bp[(size_t)row * KPAD + 4096 + tid] = __float2bfloat16(lora_up[row * R_DIM + tid]);
  } else if (tid < 64) {
    Bp[(size_t)row * KPAD + 4096 + tid] = __float2bfloat16(0.f);
  }
}

// ---------------------------------------------------------------------------
// ldT[r][k] = bf16(lora_down[k][r])  -- tiny transpose so the lora MFMA
// kernel can vector-load B fragments in [n][k] layout.
// ---------------------------------------------------------------------------
__global__ __launch_bounds__(256) void ldT_kernel(
    const float* __restrict__ ld, bf16_t* __restrict__ ldT) {
  const int k = blockIdx.x * 256 + threadIdx.x;
  float v[R_DIM];
#pragma unroll
  for (int i = 0; i < R_DIM / 4; ++i) {
    float4 a = *(const float4*)(ld + (size_t)k * R_DIM + i * 4);
    v[i*4+0] = a.x; v[i*4+1] = a.y; v[i*4+2] = a.z; v[i*4+3] = a.w;
  }
#pragma unroll
  for (int r = 0; r < R_DIM; ++r)
    ldT[(size_t)r * K_DIM + k] = __float2bfloat16(v[r]);
}

// ---------------------------------------------------------------------------
// t = (x*smooth) @ lora_down  [M x 32] via MFMA, written bf16 into Ap cols
// 4096..4127. Grid = 256 blocks of 32 rows; 4 waves, each wave owns one
// 16x16 fragment (w>>1 -> row half, w&1 -> col half), full K sweep.
// ---------------------------------------------------------------------------
__global__ __launch_bounds__(256) void lora_mfma_kernel(
    const float* __restrict__ x, const float* __restrict__ smooth,
    const bf16_t* __restrict__ ldT, bf16_t* __restrict__ Ap) {
  const int tid  = threadIdx.x;
  const int w    = tid >> 6;
  const int lane = tid & 63;
  const int m0   = blockIdx.x * 32;

  const int mrow = m0 + (w >> 1) * 16 + (lane & 15);
  const int ncol = (w & 1) * 16 + (lane & 15);
  const float* xr = x + (size_t)mrow * K_DIM;
  const bf16_t* br = ldT + (size_t)ncol * K_DIM;

  f32x4 acc = {0.f, 0.f, 0.f, 0.f};
  union { bf16_t h[8]; bf16x8 v; } au;

  for (int k = 0; k < K_DIM; k += 32) {
    const int kf = k + (lane >> 4) * 8;
    float4 x0 = *(const float4*)(xr + kf);
    float4 x1 = *(const float4*)(xr + kf + 4);
    float4 s0 = *(const float4*)(smooth + kf);
    float4 s1 = *(const float4*)(smooth + kf + 4);
    au.h[0] = __float2bfloat16(x0.x * s0.x);
    au.h[1] = __float2bfloat16(x0.y * s0.y);
    au.h[2] = __float2bfloat16(x0.z * s0.z);
    au.h[3] = __float2bfloat16(x0.w * s0.w);
    au.h[4] = __float2bfloat16(x1.x * s1.x);
    au.h[5] = __float2bfloat16(x1.y * s1.y);
    au.h[6] = __float2bfloat16(x1.z * s1.z);
    au.h[7] = __float2bfloat16(x1.w * s1.w);
    bf16x8 bv = *(const bf16x8*)(br + kf);
    acc = __builtin_amdgcn_mfma_f32_16x16x32_bf16(au.v, bv, acc, 0, 0, 0);
  }

  const int orow = m0 + (w >> 1) * 16 + (lane >> 4) * 4;
  const int ocol = 4096 + ncol;
#pragma unroll
  for (int q = 0; q < 4; ++q)
    Ap[(size_t)(orow + q) * KPAD + ocol] = __float2bfloat16(acc[q]);
}

// ---------------------------------------------------------------------------
// C[M][N] = Ap[M][KPAD] @ Bp[N][KPAD]^T + bias.  m97-structure + T2 swizzle:
// 128x128 tile, BK=64, 4 waves (2x2), 4x4 16x16x32 frags/wave,
// global_load_lds width-16 staging with inverse-swizzled global source,
// XOR-swizzled ds_read (byte ^= (row&7)<<4), XCD-swizzled 1D grid.
// ---------------------------------------------------------------------------
#define BM 128
#define BN 128
#define BK 64

__global__ __launch_bounds__(256) void gemm_kernel(
    const bf16_t* __restrict__ A, const bf16_t* __restrict__ B,
    const float* __restrict__ bias, float* __restrict__ C) {
  // XCD-aware swizzle: nwg = 2048, divisible by 8
  const int nwg = (M_DIM / BM) * (N_DIM / BN);
  const int cpx = nwg >> 3;
  const int wg  = blockIdx.x;
  const int swz = (wg & 7) * cpx + (wg >> 3);
  const int bn  = swz & (N_DIM / BN - 1);   // 0..31
  const int bm  = swz >> 5;                 // 0..63

  __shared__ bf16_t As[BM][BK];   // 16 KiB
  __shared__ bf16_t Bs[BN][BK];   // 16 KiB

  const int tid  = threadIdx.x;
  const int lane = tid & 63;
  const int wid  = tid >> 6;      // 0..3
  const int wm   = wid >> 1;      // 0..1
  const int wn   = wid & 1;       // 0..1

  f32x4 acc[4][4] = {};

  // staging geometry: thread t stages 16B at LINEAR LDS offset t*16 + j*4096.
  // LDS granule (srow, slot) must hold global granule slot^(srow&7) so that
  // the swizzled read (below) recovers the right data (both-sides rule #21).
  const int srow = tid >> 3;                         // 0..31 (row within group)
  const int slot = tid & 7;                          // 16B granule in row
  const int gcol = ((slot ^ (srow & 7)) * 8);        // inverse-swizzled source col
  const int dcol = slot * 8;                         // linear dest col
  const bf16_t* Ag = A + ((size_t)(bm * BM + srow)) * KPAD + gcol;
  const bf16_t* Bg = B + ((size_t)(bn * BN + srow)) * KPAD + gcol;

  for (int kt = 0; kt < KPAD; kt += BK) {
#pragma unroll
    for (int j = 0; j < 4; ++j) {   // j*32 keeps (row&7) = (srow&7)
      stage16(Ag + (size_t)(j * 32) * KPAD + kt, &As[srow + j * 32][dcol]);
      stage16(Bg + (size_t)(j * 32) * KPAD + kt, &Bs[srow + j * 32][dcol]);
    }
    __syncthreads();   // compiler drains vmcnt before s_barrier

#pragma unroll
    for (int ks = 0; ks < BK; ks += 32) {
      bf16x8 af[4], bfr[4];
      // granule index of the fragment's k-range, then XOR row-swizzle:
      // row = ...(lane&15) -> (row&7) = (lane&7)
      const int g    = (ks >> 3) + (lane >> 4);
      const int rcol = (g ^ (lane & 7)) * 8;
#pragma unroll
      for (int i = 0; i < 4; ++i) {
        af[i]  = *(const bf16x8*)&As[wm * 64 + i * 16 + (lane & 15)][rcol];
        bfr[i] = *(const bf16x8*)&Bs[wn * 64 + i * 16 + (lane & 15)][rcol];
      }
#pragma unroll
      for (int i = 0; i < 4; ++i)
#pragma unroll
        for (int j = 0; j < 4; ++j)
          acc[i][j] = __builtin_amdgcn_mfma_f32_16x16x32_bf16(af[i], bfr[j], acc[i][j], 0, 0, 0);
    }
    __syncthreads();
  }

  // epilogue: C/D layout col = lane&15, row = (lane>>4)*4 + reg
  const int coln = lane & 15;
  const int rowq = (lane >> 4) * 4;
#pragma unroll
  for (int j = 0; j < 4; ++j) {
    const int gc = bn * BN + wn * 64 + j * 16 + coln;
    const float bv = bias[gc];
#pragma unroll
    for (int i = 0; i < 4; ++i) {
      const int gr = bm * BM + wm * 64 + i * 16 + rowq;
#pragma unroll
      for (int q = 0; q < 4; ++q)
        C[(size_t)(gr + q) * N_DIM + gc] = acc[i][j][q] + bv;
    }
  }
}

// ---------------------------------------------------------------------------
extern "C" void kernel_launch(void* const* d_in, const int* in_sizes, int n_in,
                              void* d_out, int out_size, void* d_ws, size_t ws_size,
                              hipStream_t stream) {
  const float* x         = (const float*)d_in[0];
  const float* w_res     = (const float*)d_in[1];
  const float* lora_down = (const float*)d_in[2];
  const float* lora_up   = (const float*)d_in[3];
  const float* smooth    = (const float*)d_in[4];
  const float* b         = (const float*)d_in[5];
  float* out = (float*)d_out;

  // workspace: Ap [M][KPAD] bf16 (68.2 MB), Bp [N][KPAD] bf16 (34.1 MB),
  // ldT [R][K] bf16 (256 KB)
  bf16_t* Ap  = (bf16_t*)d_ws;
  bf16_t* Bp  = Ap + (size_t)M_DIM * KPAD;
  bf16_t* ldT = Bp + (size_t)N_DIM * KPAD;

  quant_x_kernel<<<M_DIM, 256, 0, stream>>>(x, smooth, Ap);
  quant_w_kernel<<<N_DIM, 256, 0, stream>>>(w_res, lora_up, Bp);
  ldT_kernel<<<K_DIM / 256, 256, 0, stream>>>(lora_down, ldT);
  lora_mfma_kernel<<<M_DIM / 32, 256, 0, stream>>>(x, smooth, ldT, Ap);
  gemm_kernel<<<(M_DIM / BM) * (N_DIM / BN), 256, 0, stream>>>(Ap, Bp, b, out);
}

// Round 3
// 370.128 us; speedup vs baseline: 2.3450x; 1.4046x over previous
//
#include <hip/hip_runtime.h>
#include <hip/hip_bf16.h>
#include <stdint.h>

#define M_DIM 8192
#define N_DIM 4096
#define K_DIM 4096
#define R_DIM 32
#define KPAD  4160   // 4096 quant cols + 32 lora cols + 32 zero pad = 65 * 64
#define NT    65     // K-tiles of 64
#define QMAXF 7.0f

using bf16_t = __hip_bfloat16;
typedef __attribute__((ext_vector_type(4))) float f32x4;
typedef __attribute__((ext_vector_type(8))) short bf16x8;

// ---------------------------------------------------------------------------
// async global->LDS 16B stage (LDS dest = wave-uniform base + lane*16)
// ---------------------------------------------------------------------------
__device__ __forceinline__ void stage16(const void* g, void* l) {
#if defined(__has_builtin) && __has_builtin(__builtin_amdgcn_global_load_lds)
  __builtin_amdgcn_global_load_lds(
      (const __attribute__((address_space(1))) unsigned int*)g,
      (__attribute__((address_space(3))) unsigned int*)l, 16, 0, 0);
#else
  *(uint4*)l = *(const uint4*)g;
#endif
}

// ---------------------------------------------------------------------------
// Quantize x (with smooth) -> bf16 into Ap[M][KPAD] cols 0..4095; zero pad
// cols 4128..4159. Cols 4096..4127 (t = xs@lora_down) written by lora kernel.
// ---------------------------------------------------------------------------
__global__ __launch_bounds__(256) void quant_x_kernel(
    const float* __restrict__ x, const float* __restrict__ smooth,
    bf16_t* __restrict__ Ap) {
  const int row = blockIdx.x;
  const int tid = threadIdx.x;
  const int k0  = tid * 16;                 // 16 elems/thread, group64 = 4 threads
  const float* xr = x + (size_t)row * K_DIM + k0;
  const float* sr = smooth + k0;

  float v[16];
#pragma unroll
  for (int i = 0; i < 4; ++i) {
    float4 xv = *(const float4*)(xr + i * 4);
    float4 sv = *(const float4*)(sr + i * 4);
    v[i*4+0] = xv.x * sv.x; v[i*4+1] = xv.y * sv.y;
    v[i*4+2] = xv.z * sv.z; v[i*4+3] = xv.w * sv.w;
  }
  float am = 0.f;
#pragma unroll
  for (int i = 0; i < 16; ++i) am = fmaxf(am, fabsf(v[i]));
  am = fmaxf(am, __shfl_xor(am, 1));
  am = fmaxf(am, __shfl_xor(am, 2));
  const float scale = fmaxf(am / QMAXF, 1e-8f);

  alignas(16) bf16_t o[16];
#pragma unroll
  for (int i = 0; i < 16; ++i) {
    float q = rintf(v[i] / scale);          // IEEE div + round-half-even = jnp
    q = fminf(fmaxf(q, -8.f), 7.f);
    o[i] = __float2bfloat16(q * scale);
  }
  bf16_t* dst = Ap + (size_t)row * KPAD + k0;
  ((uint4*)dst)[0] = ((uint4*)o)[0];
  ((uint4*)dst)[1] = ((uint4*)o)[1];

  if (tid < 32) Ap[(size_t)row * KPAD + 4128 + tid] = __float2bfloat16(0.f);
}

// ---------------------------------------------------------------------------
// Quantize w_res -> bf16 into Bp[N][KPAD] cols 0..4095; lora_up into cols
// 4096..4127; zeros into 4128..4159.
// ---------------------------------------------------------------------------
__global__ __launch_bounds__(256) void quant_w_kernel(
    const float* __restrict__ w, const float* __restrict__ lora_up,
    bf16_t* __restrict__ Bp) {
  const int row = blockIdx.x;
  const int tid = threadIdx.x;
  const int k0  = tid * 16;
  const float* wr = w + (size_t)row * K_DIM + k0;

  float v[16];
#pragma unroll
  for (int i = 0; i < 4; ++i) {
    float4 wv = *(const float4*)(wr + i * 4);
    v[i*4+0] = wv.x; v[i*4+1] = wv.y; v[i*4+2] = wv.z; v[i*4+3] = wv.w;
  }
  float am = 0.f;
#pragma unroll
  for (int i = 0; i < 16; ++i) am = fmaxf(am, fabsf(v[i]));
  am = fmaxf(am, __shfl_xor(am, 1));
  am = fmaxf(am, __shfl_xor(am, 2));
  const float scale = fmaxf(am / QMAXF, 1e-8f);

  alignas(16) bf16_t o[16];
#pragma unroll
  for (int i = 0; i < 16; ++i) {
    float q = rintf(v[i] / scale);
    q = fminf(fmaxf(q, -8.f), 7.f);
    o[i] = __float2bfloat16(q * scale);
  }
  bf16_t* dst = Bp + (size_t)row * KPAD + k0;
  ((uint4*)dst)[0] = ((uint4*)o)[0];
  ((uint4*)dst)[1] = ((uint4*)o)[1];

  if (tid < 32) {
    Bp[(size_t)row * KPAD + 4096 + tid] = __float2bfloat16(lora_up[row * R_DIM + tid]);
  } else if (tid < 64) {
    Bp[(size_t)row * KPAD + 4096 + tid] = __float2bfloat16(0.f);
  }
}

// ---------------------------------------------------------------------------
// ldT[r][k] = bf16(lora_down[k][r])
// ---------------------------------------------------------------------------
__global__ __launch_bounds__(256) void ldT_kernel(
    const float* __restrict__ ld, bf16_t* __restrict__ ldT) {
  const int k = blockIdx.x * 256 + threadIdx.x;
  float v[R_DIM];
#pragma unroll
  for (int i = 0; i < R_DIM / 4; ++i) {
    float4 a = *(const float4*)(ld + (size_t)k * R_DIM + i * 4);
    v[i*4+0] = a.x; v[i*4+1] = a.y; v[i*4+2] = a.z; v[i*4+3] = a.w;
  }
#pragma unroll
  for (int r = 0; r < R_DIM; ++r)
    ldT[(size_t)r * K_DIM + k] = __float2bfloat16(v[r]);
}

// ---------------------------------------------------------------------------
// t = (x*smooth) @ lora_down  [M x 32] via MFMA -> Ap cols 4096..4127.
// ---------------------------------------------------------------------------
__global__ __launch_bounds__(256) void lora_mfma_kernel(
    const float* __restrict__ x, const float* __restrict__ smooth,
    const bf16_t* __restrict__ ldT, bf16_t* __restrict__ Ap) {
  const int tid  = threadIdx.x;
  const int w    = tid >> 6;
  const int lane = tid & 63;
  const int m0   = blockIdx.x * 32;

  const int mrow = m0 + (w >> 1) * 16 + (lane & 15);
  const int ncol = (w & 1) * 16 + (lane & 15);
  const float* xr = x + (size_t)mrow * K_DIM;
  const bf16_t* br = ldT + (size_t)ncol * K_DIM;

  f32x4 acc = {0.f, 0.f, 0.f, 0.f};
  union { bf16_t h[8]; bf16x8 v; } au;

  for (int k = 0; k < K_DIM; k += 32) {
    const int kf = k + (lane >> 4) * 8;
    float4 x0 = *(const float4*)(xr + kf);
    float4 x1 = *(const float4*)(xr + kf + 4);
    float4 s0 = *(const float4*)(smooth + kf);
    float4 s1 = *(const float4*)(smooth + kf + 4);
    au.h[0] = __float2bfloat16(x0.x * s0.x);
    au.h[1] = __float2bfloat16(x0.y * s0.y);
    au.h[2] = __float2bfloat16(x0.z * s0.z);
    au.h[3] = __float2bfloat16(x0.w * s0.w);
    au.h[4] = __float2bfloat16(x1.x * s1.x);
    au.h[5] = __float2bfloat16(x1.y * s1.y);
    au.h[6] = __float2bfloat16(x1.z * s1.z);
    au.h[7] = __float2bfloat16(x1.w * s1.w);
    bf16x8 bv = *(const bf16x8*)(br + kf);
    acc = __builtin_amdgcn_mfma_f32_16x16x32_bf16(au.v, bv, acc, 0, 0, 0);
  }

  const int orow = m0 + (w >> 1) * 16 + (lane >> 4) * 4;
  const int ocol = 4096 + ncol;
#pragma unroll
  for (int q = 0; q < 4; ++q)
    Ap[(size_t)(orow + q) * KPAD + ocol] = __float2bfloat16(acc[q]);
}

// ---------------------------------------------------------------------------
// 256x256x64 8-phase GEMM (T2+T3+T4+T5).  8 waves (2M x 4N), per-wave output
// 128x64.  LDS: 2 dbuf x (A[256][64] + B[256][64]) bf16 = 128 KiB dynamic.
// A tile stored quadrant-major: lds_row = q*64 + wm*32 + r  so that
//   A-half0 (lds rows 0..127)  = quadrant rows q0,q1 of both wave-halves,
//   A-half1 (lds rows 128..255)= q2,q3.  B-half h = n-rows h*128..h*128+127.
// Read windows: B: P1 only (reg-cached); A-half0: P1-P2; A-half1: P3-P4.
// Stage ring: P1: A2(u+1)->buf^1 | P2: B1(u+2)->buf | P3: B2(u+2)->buf |
//             P4: A1(u+2)->buf, then s_waitcnt vmcnt(6)  (3 half-tiles stay
//             in flight across the barrier; tail uses vmcnt(0)).
// Swizzle: 16B granule ^= (row&7) on both stage-source and ds_read (0-conflict
// verified in round 2).
// ---------------------------------------------------------------------------
__global__ __launch_bounds__(512, 2) void gemm_kernel(
    const bf16_t* __restrict__ A, const bf16_t* __restrict__ B,
    const float* __restrict__ bias, float* __restrict__ C) {
  extern __shared__ __align__(16) bf16_t lds[];   // 65536 elems = 128 KiB

  // XCD-aware swizzle: nwg = 512, divisible by 8
  const int wg  = blockIdx.x;
  const int swz = (wg & 7) * 64 + (wg >> 3);
  const int bn  = swz & 15;    // 0..15
  const int bm  = swz >> 4;    // 0..31

  const int tid  = threadIdx.x;
  const int lane = tid & 63;
  const int wid  = tid >> 6;     // 0..7
  const int wm   = wid >> 2;     // 0..1
  const int wn   = wid & 3;      // 0..3

  const int lr = lane & 15;      // frag row within 16
  const int lg = lane >> 4;      // k-granule subindex 0..3
  const int l7 = lane & 7;
  const int gk0 = ((0 + lg) ^ l7) * 8;   // swizzled elem offset, k-half 0
  const int gk1 = ((4 + lg) ^ l7) * 8;   // k-half 1

  // staging geometry: thread stages 16B granules; per half-tile 2 loads.
  const int sr   = tid >> 3;                 // 0..63 row-in-64-group
  const int sl   = tid & 7;                  // granule slot
  const int gcol = (sl ^ (sr & 7)) * 8;      // inverse-swizzled source col
  // A source row for (h,l): bm*256 + ((sr>>5)&1)*128 + (h*2+l)*32 + (sr&31)
  const bf16_t* Abase = A + (size_t)(bm * 256 + ((sr >> 5) & 1) * 128 + (sr & 31)) * KPAD + gcol;
  // B source row for (h,l): bn*256 + h*128 + l*64 + sr
  const bf16_t* Bbase = B + (size_t)(bn * 256 + sr) * KPAD + gcol;
  bf16_t* ldsb = lds;

#define STAGE_A(buf, h, kt) do {                                               \
    stage16(Abase + (size_t)((h) * 2 + 0) * 32 * KPAD + (kt) * 64,             \
            ldsb + (buf) * 32768 + (h) * 8192 + 0 * 4096 + tid * 8);           \
    stage16(Abase + (size_t)((h) * 2 + 1) * 32 * KPAD + (kt) * 64,             \
            ldsb + (buf) * 32768 + (h) * 8192 + 1 * 4096 + tid * 8);           \
  } while (0)
#define STAGE_B(buf, h, kt) do {                                               \
    stage16(Bbase + (size_t)((h) * 128 + 0) * KPAD + (kt) * 64,                \
            ldsb + (buf) * 32768 + 16384 + (h) * 8192 + 0 * 4096 + tid * 8);   \
    stage16(Bbase + (size_t)((h) * 128 + 64) * KPAD + (kt) * 64,               \
            ldsb + (buf) * 32768 + 16384 + (h) * 8192 + 1 * 4096 + tid * 8);   \
  } while (0)

  f32x4  acc[8][4] = {};
  bf16x8 aF[2][2];
  bf16x8 bF[4][2];

#define LOAD_A(q) do {                                                         \
    const bf16_t* pa_ = ldsb + cur * 32768 + ((q) * 64 + wm * 32 + lr) * 64;   \
    aF[0][0] = *(const bf16x8*)(pa_ + gk0);                                    \
    aF[0][1] = *(const bf16x8*)(pa_ + gk1);                                    \
    aF[1][0] = *(const bf16x8*)(pa_ + 1024 + gk0);                             \
    aF[1][1] = *(const bf16x8*)(pa_ + 1024 + gk1);                             \
  } while (0)
#define LOAD_B() do {                                                          \
    _Pragma("unroll")                                                          \
    for (int j = 0; j < 4; ++j) {                                              \
      const bf16_t* pb_ = ldsb + cur * 32768 + 16384 + (wn * 64 + j * 16 + lr) * 64; \
      bF[j][0] = *(const bf16x8*)(pb_ + gk0);                                  \
      bF[j][1] = *(const bf16x8*)(pb_ + gk1);                                  \
    }                                                                          \
  } while (0)
#define MFMA_Q(q) do {                                                         \
    _Pragma("unroll")                                                          \
    for (int i = 0; i < 2; ++i)                                                \
      _Pragma("unroll")                                                        \
      for (int j = 0; j < 4; ++j) {                                            \
        acc[(q)*2+i][j] = __builtin_amdgcn_mfma_f32_16x16x32_bf16(             \
            aF[i][0], bF[j][0], acc[(q)*2+i][j], 0, 0, 0);                     \
        acc[(q)*2+i][j] = __builtin_amdgcn_mfma_f32_16x16x32_bf16(             \
            aF[i][1], bF[j][1], acc[(q)*2+i][j], 0, 0, 0);                     \
      }                                                                        \
  } while (0)
#define PHASE_TAIL(q) do {                                                     \
    __builtin_amdgcn_s_barrier();                                              \
    asm volatile("s_waitcnt lgkmcnt(0)" ::: "memory");                         \
    __builtin_amdgcn_s_setprio(1);                                             \
    MFMA_Q(q);                                                                 \
    __builtin_amdgcn_s_setprio(0);                                             \
    __builtin_amdgcn_s_barrier();                                              \
  } while (0)

  // ---- prologue: stage ktile0 fully + ktile1's B1,B2,A1; wait ktile0 ----
  STAGE_B(0, 0, 0); STAGE_B(0, 1, 0); STAGE_A(0, 0, 0); STAGE_A(0, 1, 0);
  STAGE_B(1, 0, 1); STAGE_B(1, 1, 1); STAGE_A(1, 0, 1);
  asm volatile("s_waitcnt vmcnt(6)" ::: "memory");
  __builtin_amdgcn_s_barrier();

  for (int u = 0; u < NT; ++u) {
    const int cur = u & 1;
    // ---- P1: read all B-frags + A quadrant 0; stage A2(u+1) into other buf
    LOAD_B();
    LOAD_A(0);
    if (u + 1 < NT) STAGE_A(cur ^ 1, 1, u + 1);
    PHASE_TAIL(0);
    // ---- P2: A quadrant 1; stage B1(u+2) (B slot free after P1)
    LOAD_A(1);
    if (u + 2 < NT) STAGE_B(cur, 0, u + 2);
    PHASE_TAIL(1);
    // ---- P3: A quadrant 2; stage B2(u+2)
    LOAD_A(2);
    if (u + 2 < NT) STAGE_B(cur, 1, u + 2);
    PHASE_TAIL(2);
    // ---- P4: A quadrant 3; stage A1(u+2) (A-half0 free after P2); counted wait
    LOAD_A(3);
    if (u + 2 < NT) {
      STAGE_A(cur, 0, u + 2);
      asm volatile("s_waitcnt vmcnt(6)" ::: "memory");
    } else {
      asm volatile("s_waitcnt vmcnt(0)" ::: "memory");
    }
    PHASE_TAIL(3);
  }

  // ---- epilogue: C/D layout col = lane&15, row = (lane>>4)*4 + e ----
  const int colb = bn * 256 + wn * 64 + lr;
  const int rowb = bm * 256 + wm * 128 + lg * 4;
#pragma unroll
  for (int j = 0; j < 4; ++j) {
    const int gc = colb + j * 16;
    const float bv = bias[gc];
#pragma unroll
    for (int q = 0; q < 4; ++q)
#pragma unroll
      for (int i = 0; i < 2; ++i) {
        const int gr = rowb + q * 32 + i * 16;
#pragma unroll
        for (int e = 0; e < 4; ++e)
          C[(size_t)(gr + e) * N_DIM + gc] = acc[q * 2 + i][j][e] + bv;
      }
  }
#undef STAGE_A
#undef STAGE_B
#undef LOAD_A
#undef LOAD_B
#undef MFMA_Q
#undef PHASE_TAIL
}

// ---------------------------------------------------------------------------
extern "C" void kernel_launch(void* const* d_in, const int* in_sizes, int n_in,
                              void* d_out, int out_size, void* d_ws, size_t ws_size,
                              hipStream_t stream) {
  const float* x         = (const float*)d_in[0];
  const float* w_res     = (const float*)d_in[1];
  const float* lora_down = (const float*)d_in[2];
  const float* lora_up   = (const float*)d_in[3];
  const float* smooth    = (const float*)d_in[4];
  const float* b         = (const float*)d_in[5];
  float* out = (float*)d_out;

  // workspace: Ap [M][KPAD] bf16 (68.2 MB), Bp [N][KPAD] bf16 (34.1 MB),
  // ldT [R][K] bf16 (256 KB)
  bf16_t* Ap  = (bf16_t*)d_ws;
  bf16_t* Bp  = Ap + (size_t)M_DIM * KPAD;
  bf16_t* ldT = Bp + (size_t)N_DIM * KPAD;

  // allow 128 KiB dynamic LDS (idempotent, host-side, capture-safe)
  hipFuncSetAttribute((const void*)gemm_kernel,
                      hipFuncAttributeMaxDynamicSharedMemorySize, 131072);

  quant_x_kernel<<<M_DIM, 256, 0, stream>>>(x, smooth, Ap);
  quant_w_kernel<<<N_DIM, 256, 0, stream>>>(w_res, lora_up, Bp);
  ldT_kernel<<<K_DIM / 256, 256, 0, stream>>>(lora_down, ldT);
  lora_mfma_kernel<<<M_DIM / 32, 256, 0, stream>>>(x, smooth, ldT, Ap);
  gemm_kernel<<<(M_DIM / 256) * (N_DIM / 256), 512, 131072, stream>>>(Ap, Bp, b, out);
}

// Round 4
// 366.734 us; speedup vs baseline: 2.3667x; 1.0093x over previous
//
#include <hip/hip_runtime.h>
#include <hip/hip_bf16.h>
#include <stdint.h>

#define M_DIM 8192
#define N_DIM 4096
#define K_DIM 4096
#define R_DIM 32
#define KPAD  4160   // 4096 quant cols + 32 lora cols + 32 zero pad = 65 * 64
#define NT    65     // K-tiles of 64
#define QMAXF 7.0f

using bf16_t = __hip_bfloat16;
typedef __attribute__((ext_vector_type(4))) float f32x4;
typedef __attribute__((ext_vector_type(8))) short bf16x8;

// ---------------------------------------------------------------------------
// async global->LDS 16B stage (LDS dest = wave-uniform base + lane*16)
// ---------------------------------------------------------------------------
__device__ __forceinline__ void stage16(const void* g, void* l) {
#if defined(__has_builtin) && __has_builtin(__builtin_amdgcn_global_load_lds)
  __builtin_amdgcn_global_load_lds(
      (const __attribute__((address_space(1))) unsigned int*)g,
      (__attribute__((address_space(3))) unsigned int*)l, 16, 0, 0);
#else
  *(uint4*)l = *(const uint4*)g;
#endif
}

// ---------------------------------------------------------------------------
// Quantize x (with smooth) -> bf16 into Ap[M][KPAD] cols 0..4095; zero pad
// cols 4128..4159. Cols 4096..4127 (t = xs@lora_down) written by lora kernel.
// ---------------------------------------------------------------------------
__global__ __launch_bounds__(256) void quant_x_kernel(
    const float* __restrict__ x, const float* __restrict__ smooth,
    bf16_t* __restrict__ Ap) {
  const int row = blockIdx.x;
  const int tid = threadIdx.x;
  const int k0  = tid * 16;                 // 16 elems/thread, group64 = 4 threads
  const float* xr = x + (size_t)row * K_DIM + k0;
  const float* sr = smooth + k0;

  float v[16];
#pragma unroll
  for (int i = 0; i < 4; ++i) {
    float4 xv = *(const float4*)(xr + i * 4);
    float4 sv = *(const float4*)(sr + i * 4);
    v[i*4+0] = xv.x * sv.x; v[i*4+1] = xv.y * sv.y;
    v[i*4+2] = xv.z * sv.z; v[i*4+3] = xv.w * sv.w;
  }
  float am = 0.f;
#pragma unroll
  for (int i = 0; i < 16; ++i) am = fmaxf(am, fabsf(v[i]));
  am = fmaxf(am, __shfl_xor(am, 1));
  am = fmaxf(am, __shfl_xor(am, 2));
  const float scale = fmaxf(am / QMAXF, 1e-8f);

  alignas(16) bf16_t o[16];
#pragma unroll
  for (int i = 0; i < 16; ++i) {
    float q = rintf(v[i] / scale);          // IEEE div + round-half-even = jnp
    q = fminf(fmaxf(q, -8.f), 7.f);
    o[i] = __float2bfloat16(q * scale);
  }
  bf16_t* dst = Ap + (size_t)row * KPAD + k0;
  ((uint4*)dst)[0] = ((uint4*)o)[0];
  ((uint4*)dst)[1] = ((uint4*)o)[1];

  if (tid < 32) Ap[(size_t)row * KPAD + 4128 + tid] = __float2bfloat16(0.f);
}

// ---------------------------------------------------------------------------
// Quantize w_res -> bf16 into Bp[N][KPAD] cols 0..4095; lora_up into cols
// 4096..4127; zeros into 4128..4159.
// ---------------------------------------------------------------------------
__global__ __launch_bounds__(256) void quant_w_kernel(
    const float* __restrict__ w, const float* __restrict__ lora_up,
    bf16_t* __restrict__ Bp) {
  const int row = blockIdx.x;
  const int tid = threadIdx.x;
  const int k0  = tid * 16;
  const float* wr = w + (size_t)row * K_DIM + k0;

  float v[16];
#pragma unroll
  for (int i = 0; i < 4; ++i) {
    float4 wv = *(const float4*)(wr + i * 4);
    v[i*4+0] = wv.x; v[i*4+1] = wv.y; v[i*4+2] = wv.z; v[i*4+3] = wv.w;
  }
  float am = 0.f;
#pragma unroll
  for (int i = 0; i < 16; ++i) am = fmaxf(am, fabsf(v[i]));
  am = fmaxf(am, __shfl_xor(am, 1));
  am = fmaxf(am, __shfl_xor(am, 2));
  const float scale = fmaxf(am / QMAXF, 1e-8f);

  alignas(16) bf16_t o[16];
#pragma unroll
  for (int i = 0; i < 16; ++i) {
    float q = rintf(v[i] / scale);
    q = fminf(fmaxf(q, -8.f), 7.f);
    o[i] = __float2bfloat16(q * scale);
  }
  bf16_t* dst = Bp + (size_t)row * KPAD + k0;
  ((uint4*)dst)[0] = ((uint4*)o)[0];
  ((uint4*)dst)[1] = ((uint4*)o)[1];

  if (tid < 32) {
    Bp[(size_t)row * KPAD + 4096 + tid] = __float2bfloat16(lora_up[row * R_DIM + tid]);
  } else if (tid < 64) {
    Bp[(size_t)row * KPAD + 4096 + tid] = __float2bfloat16(0.f);
  }
}

// ---------------------------------------------------------------------------
// ldT[r][k] = bf16(lora_down[k][r])
// ---------------------------------------------------------------------------
__global__ __launch_bounds__(256) void ldT_kernel(
    const float* __restrict__ ld, bf16_t* __restrict__ ldT) {
  const int k = blockIdx.x * 256 + threadIdx.x;
  float v[R_DIM];
#pragma unroll
  for (int i = 0; i < R_DIM / 4; ++i) {
    float4 a = *(const float4*)(ld + (size_t)k * R_DIM + i * 4);
    v[i*4+0] = a.x; v[i*4+1] = a.y; v[i*4+2] = a.z; v[i*4+3] = a.w;
  }
#pragma unroll
  for (int r = 0; r < R_DIM; ++r)
    ldT[(size_t)r * K_DIM + k] = __float2bfloat16(v[r]);
}

// ---------------------------------------------------------------------------
// t = (x*smooth) @ lora_down  [M x 32] via MFMA -> Ap cols 4096..4127.
// ---------------------------------------------------------------------------
__global__ __launch_bounds__(256) void lora_mfma_kernel(
    const float* __restrict__ x, const float* __restrict__ smooth,
    const bf16_t* __restrict__ ldT, bf16_t* __restrict__ Ap) {
  const int tid  = threadIdx.x;
  const int w    = tid >> 6;
  const int lane = tid & 63;
  const int m0   = blockIdx.x * 32;

  const int mrow = m0 + (w >> 1) * 16 + (lane & 15);
  const int ncol = (w & 1) * 16 + (lane & 15);
  const float* xr = x + (size_t)mrow * K_DIM;
  const bf16_t* br = ldT + (size_t)ncol * K_DIM;

  f32x4 acc = {0.f, 0.f, 0.f, 0.f};
  union { bf16_t h[8]; bf16x8 v; } au;

  for (int k = 0; k < K_DIM; k += 32) {
    const int kf = k + (lane >> 4) * 8;
    float4 x0 = *(const float4*)(xr + kf);
    float4 x1 = *(const float4*)(xr + kf + 4);
    float4 s0 = *(const float4*)(smooth + kf);
    float4 s1 = *(const float4*)(smooth + kf + 4);
    au.h[0] = __float2bfloat16(x0.x * s0.x);
    au.h[1] = __float2bfloat16(x0.y * s0.y);
    au.h[2] = __float2bfloat16(x0.z * s0.z);
    au.h[3] = __float2bfloat16(x0.w * s0.w);
    au.h[4] = __float2bfloat16(x1.x * s1.x);
    au.h[5] = __float2bfloat16(x1.y * s1.y);
    au.h[6] = __float2bfloat16(x1.z * s1.z);
    au.h[7] = __float2bfloat16(x1.w * s1.w);
    bf16x8 bv = *(const bf16x8*)(br + kf);
    acc = __builtin_amdgcn_mfma_f32_16x16x32_bf16(au.v, bv, acc, 0, 0, 0);
  }

  const int orow = m0 + (w >> 1) * 16 + (lane >> 4) * 4;
  const int ocol = 4096 + ncol;
#pragma unroll
  for (int q = 0; q < 4; ++q)
    Ap[(size_t)(orow + q) * KPAD + ocol] = __float2bfloat16(acc[q]);
}

// ---------------------------------------------------------------------------
// 256x256x64 8-phase GEMM, B-fragments pipelined one ktile ahead.
// 8 waves (2M x 4N), per-wave output 128x64.  LDS: 2 dbuf x (A[256][64] +
// B[256][64]) bf16 = 128 KiB dynamic.  A quadrant-major (lds_row = q*64 +
// wm*32 + r).  B-frag regs double-buffered (bA/bB): B(u+1) read during P4
// tail of u (post vmcnt(6)+barrier => staged data visible), overlapping the
// MFMA cluster; consumed during all 4 phases of u+1.  A-frags read
// same-phase (issued pre-barrier, latency hidden by barrier wait).
// Stage ring: P1: A2(u+1)->buf^1 | P2: B1(u+2)->buf | P3: B2(u+2)->buf |
//             P4: A1(u+2)->buf + vmcnt(6)  (tail: vmcnt(0)).
// Swizzle: 16B granule ^= (row&7) on stage-source and ds_read (0-conflict).
// ---------------------------------------------------------------------------
__global__ __launch_bounds__(512, 2) void gemm_kernel(
    const bf16_t* __restrict__ A, const bf16_t* __restrict__ B,
    const float* __restrict__ bias, float* __restrict__ C) {
  extern __shared__ __align__(16) bf16_t lds[];   // 65536 elems = 128 KiB

  // XCD-aware swizzle: nwg = 512, divisible by 8
  const int wg  = blockIdx.x;
  const int swz = (wg & 7) * 64 + (wg >> 3);
  const int bn  = swz & 15;    // 0..15
  const int bm  = swz >> 4;    // 0..31

  const int tid  = threadIdx.x;
  const int lane = tid & 63;
  const int wid  = tid >> 6;     // 0..7
  const int wm   = wid >> 2;     // 0..1
  const int wn   = wid & 3;      // 0..3

  const int lr = lane & 15;      // frag row within 16
  const int lg = lane >> 4;      // k-granule subindex 0..3
  const int l7 = lane & 7;
  const int gk0 = ((0 + lg) ^ l7) * 8;   // swizzled elem offset, k-half 0
  const int gk1 = ((4 + lg) ^ l7) * 8;   // k-half 1

  // staging geometry
  const int sr   = tid >> 3;                 // 0..63
  const int sl   = tid & 7;                  // granule slot
  const int gcol = (sl ^ (sr & 7)) * 8;      // inverse-swizzled source col
  const bf16_t* Abase = A + (size_t)(bm * 256 + ((sr >> 5) & 1) * 128 + (sr & 31)) * KPAD + gcol;
  const bf16_t* Bbase = B + (size_t)(bn * 256 + sr) * KPAD + gcol;
  bf16_t* ldsb = lds;

#define STAGE_A(buf, h, kt) do {                                               \
    stage16(Abase + (size_t)((h) * 2 + 0) * 32 * KPAD + (kt) * 64,             \
            ldsb + (buf) * 32768 + (h) * 8192 + 0 * 4096 + tid * 8);           \
    stage16(Abase + (size_t)((h) * 2 + 1) * 32 * KPAD + (kt) * 64,             \
            ldsb + (buf) * 32768 + (h) * 8192 + 1 * 4096 + tid * 8);           \
  } while (0)
#define STAGE_B(buf, h, kt) do {                                               \
    stage16(Bbase + (size_t)((h) * 128 + 0) * KPAD + (kt) * 64,                \
            ldsb + (buf) * 32768 + 16384 + (h) * 8192 + 0 * 4096 + tid * 8);   \
    stage16(Bbase + (size_t)((h) * 128 + 64) * KPAD + (kt) * 64,               \
            ldsb + (buf) * 32768 + 16384 + (h) * 8192 + 1 * 4096 + tid * 8);   \
  } while (0)

  f32x4  acc[8][4] = {};
  bf16x8 aF[2][2];
  bf16x8 bA[4][2];   // B-frag set A (even ktiles)
  bf16x8 bB[4][2];   // B-frag set B (odd ktiles)

#define LOAD_A(q, cur) do {                                                    \
    const bf16_t* pa_ = ldsb + (cur) * 32768 + ((q) * 64 + wm * 32 + lr) * 64; \
    aF[0][0] = *(const bf16x8*)(pa_ + gk0);                                    \
    aF[0][1] = *(const bf16x8*)(pa_ + gk1);                                    \
    aF[1][0] = *(const bf16x8*)(pa_ + 1024 + gk0);                             \
    aF[1][1] = *(const bf16x8*)(pa_ + 1024 + gk1);                             \
  } while (0)
#define LOAD_BN(BN, nbuf) do {                                                 \
    _Pragma("unroll")                                                          \
    for (int j = 0; j < 4; ++j) {                                              \
      const bf16_t* pb_ = ldsb + (nbuf) * 32768 + 16384 + (wn * 64 + j * 16 + lr) * 64; \
      BN[j][0] = *(const bf16x8*)(pb_ + gk0);                                  \
      BN[j][1] = *(const bf16x8*)(pb_ + gk1);                                  \
    }                                                                          \
  } while (0)
#define MFMA_Q(q, BARR) do {                                                   \
    _Pragma("unroll")                                                          \
    for (int i = 0; i < 2; ++i)                                                \
      _Pragma("unroll")                                                        \
      for (int j = 0; j < 4; ++j) {                                            \
        acc[(q)*2+i][j] = __builtin_amdgcn_mfma_f32_16x16x32_bf16(             \
            aF[i][0], BARR[j][0], acc[(q)*2+i][j], 0, 0, 0);                   \
        acc[(q)*2+i][j] = __builtin_amdgcn_mfma_f32_16x16x32_bf16(             \
            aF[i][1], BARR[j][1], acc[(q)*2+i][j], 0, 0, 0);                   \
      }                                                                        \
  } while (0)
#define TAIL_PLAIN(q, BARR) do {                                               \
    __builtin_amdgcn_s_barrier();                                              \
    asm volatile("s_waitcnt lgkmcnt(0)" ::: "memory");                         \
    __builtin_amdgcn_s_setprio(1);                                             \
    MFMA_Q(q, BARR);                                                           \
    __builtin_amdgcn_s_setprio(0);                                             \
    __builtin_amdgcn_s_barrier();                                              \
  } while (0)

  // One ktile: phases P1-P4.  BCUR consumed, BNXT loaded in P4 tail.
#define KTILE(u, cur, BCUR, BNXT) do {                                         \
    LOAD_A(0, cur);                                                            \
    if ((u) + 1 < NT) STAGE_A((cur) ^ 1, 1, (u) + 1);                          \
    TAIL_PLAIN(0, BCUR);                                                       \
    LOAD_A(1, cur);                                                            \
    if ((u) + 2 < NT) STAGE_B(cur, 0, (u) + 2);                                \
    TAIL_PLAIN(1, BCUR);                                                       \
    LOAD_A(2, cur);                                                            \
    if ((u) + 2 < NT) STAGE_B(cur, 1, (u) + 2);                                \
    TAIL_PLAIN(2, BCUR);                                                       \
    LOAD_A(3, cur);                                                            \
    if ((u) + 2 < NT) {                                                        \
      STAGE_A(cur, 0, (u) + 2);                                                \
      asm volatile("s_waitcnt vmcnt(6)" ::: "memory");                         \
    } else {                                                                   \
      asm volatile("s_waitcnt vmcnt(0)" ::: "memory");                         \
    }                                                                          \
    __builtin_amdgcn_s_barrier();                                              \
    asm volatile("s_waitcnt lgkmcnt(0)" ::: "memory");                         \
    if ((u) + 1 < NT) LOAD_BN(BNXT, (cur) ^ 1);                                \
    __builtin_amdgcn_s_setprio(1);                                             \
    MFMA_Q(3, BCUR);                                                           \
    __builtin_amdgcn_s_setprio(0);                                             \
    __builtin_amdgcn_s_barrier();                                              \
  } while (0)

  // ---- prologue: stage ktile0 fully + ktile1's B1,B2,A1; wait ktile0;
  //      preload B(0) fragment registers ----
  STAGE_B(0, 0, 0); STAGE_B(0, 1, 0); STAGE_A(0, 0, 0); STAGE_A(0, 1, 0);
  STAGE_B(1, 0, 1); STAGE_B(1, 1, 1); STAGE_A(1, 0, 1);
  asm volatile("s_waitcnt vmcnt(6)" ::: "memory");
  __builtin_amdgcn_s_barrier();
  LOAD_BN(bA, 0);

  for (int base = 0; base < 64; base += 2) {
    KTILE(base,     0, bA, bB);
    KTILE(base + 1, 1, bB, bA);
  }
  KTILE(64, 0, bA, bB);

  // ---- epilogue: C/D layout col = lane&15, row = (lane>>4)*4 + e ----
  const int colb = bn * 256 + wn * 64 + lr;
  const int rowb = bm * 256 + wm * 128 + lg * 4;
#pragma unroll
  for (int j = 0; j < 4; ++j) {
    const int gc = colb + j * 16;
    const float bv = bias[gc];
#pragma unroll
    for (int q = 0; q < 4; ++q)
#pragma unroll
      for (int i = 0; i < 2; ++i) {
        const int gr = rowb + q * 32 + i * 16;
#pragma unroll
        for (int e = 0; e < 4; ++e)
          C[(size_t)(gr + e) * N_DIM + gc] = acc[q * 2 + i][j][e] + bv;
      }
  }
#undef STAGE_A
#undef STAGE_B
#undef LOAD_A
#undef LOAD_BN
#undef MFMA_Q
#undef TAIL_PLAIN
#undef KTILE
}

// ---------------------------------------------------------------------------
extern "C" void kernel_launch(void* const* d_in, const int* in_sizes, int n_in,
                              void* d_out, int out_size, void* d_ws, size_t ws_size,
                              hipStream_t stream) {
  const float* x         = (const float*)d_in[0];
  const float* w_res     = (const float*)d_in[1];
  const float* lora_down = (const float*)d_in[2];
  const float* lora_up   = (const float*)d_in[3];
  const float* smooth    = (const float*)d_in[4];
  const float* b         = (const float*)d_in[5];
  float* out = (float*)d_out;

  // workspace: Ap [M][KPAD] bf16 (68.2 MB), Bp [N][KPAD] bf16 (34.1 MB),
  // ldT [R][K] bf16 (256 KB)
  bf16_t* Ap  = (bf16_t*)d_ws;
  bf16_t* Bp  = Ap + (size_t)M_DIM * KPAD;
  bf16_t* ldT = Bp + (size_t)N_DIM * KPAD;

  // allow 128 KiB dynamic LDS (idempotent, host-side, capture-safe)
  hipFuncSetAttribute((const void*)gemm_kernel,
                      hipFuncAttributeMaxDynamicSharedMemorySize, 131072);

  quant_x_kernel<<<M_DIM, 256, 0, stream>>>(x, smooth, Ap);
  quant_w_kernel<<<N_DIM, 256, 0, stream>>>(w_res, lora_up, Bp);
  ldT_kernel<<<K_DIM / 256, 256, 0, stream>>>(lora_down, ldT);
  lora_mfma_kernel<<<M_DIM / 32, 256, 0, stream>>>(x, smooth, ldT, Ap);
  gemm_kernel<<<(M_DIM / 256) * (N_DIM / 256), 512, 131072, stream>>>(Ap, Bp, b, out);
}

// Round 5
// 358.691 us; speedup vs baseline: 2.4197x; 1.0224x over previous
//
#include <hip/hip_runtime.h>
#include <hip/hip_bf16.h>
#include <stdint.h>

#define M_DIM 8192
#define N_DIM 4096
#define K_DIM 4096
#define R_DIM 32
#define KPAD  4160   // 4096 quant cols + 32 lora cols + 32 zero pad = 65 * 64
#define NT    65     // K-tiles of 64
#define QMAXF 7.0f

using bf16_t = __hip_bfloat16;
typedef __attribute__((ext_vector_type(4))) float f32x4;
typedef __attribute__((ext_vector_type(8))) short bf16x8;

// ---------------------------------------------------------------------------
// async global->LDS 16B stage (LDS dest = wave-uniform base + lane*16)
// ---------------------------------------------------------------------------
__device__ __forceinline__ void stage16(const void* g, void* l) {
#if defined(__has_builtin) && __has_builtin(__builtin_amdgcn_global_load_lds)
  __builtin_amdgcn_global_load_lds(
      (const __attribute__((address_space(1))) unsigned int*)g,
      (__attribute__((address_space(3))) unsigned int*)l, 16, 0, 0);
#else
  *(uint4*)l = *(const uint4*)g;
#endif
}

// ---------------------------------------------------------------------------
// prep kernel: block-range dispatch of three independent jobs.
//   blocks [0, 8192)      : quant_x  (smooth + int4 fake-quant -> Ap cols 0..4095, pad 4128..4159)
//   blocks [8192, 12288)  : quant_w  (fake-quant -> Bp cols 0..4095, lora_up -> 4096..4127, pad)
//   blocks [12288, 12304) : ldT      (lora_down [K][R] -> bf16 ldT [R][K])
// ---------------------------------------------------------------------------
__global__ __launch_bounds__(256) void prep_kernel(
    const float* __restrict__ x, const float* __restrict__ smooth,
    const float* __restrict__ w, const float* __restrict__ lora_up,
    const float* __restrict__ ld,
    bf16_t* __restrict__ Ap, bf16_t* __restrict__ Bp,
    bf16_t* __restrict__ ldT) {
  const int bid = blockIdx.x;
  const int tid = threadIdx.x;

  if (bid < M_DIM) {                       // ---- quant_x ----
    const int row = bid;
    const int k0  = tid * 16;
    const float* xr = x + (size_t)row * K_DIM + k0;
    const float* sr = smooth + k0;

    float v[16];
#pragma unroll
    for (int i = 0; i < 4; ++i) {
      float4 xv = *(const float4*)(xr + i * 4);
      float4 sv = *(const float4*)(sr + i * 4);
      v[i*4+0] = xv.x * sv.x; v[i*4+1] = xv.y * sv.y;
      v[i*4+2] = xv.z * sv.z; v[i*4+3] = xv.w * sv.w;
    }
    float am = 0.f;
#pragma unroll
    for (int i = 0; i < 16; ++i) am = fmaxf(am, fabsf(v[i]));
    am = fmaxf(am, __shfl_xor(am, 1));
    am = fmaxf(am, __shfl_xor(am, 2));
    const float scale = fmaxf(am / QMAXF, 1e-8f);

    alignas(16) bf16_t o[16];
#pragma unroll
    for (int i = 0; i < 16; ++i) {
      float q = rintf(v[i] / scale);       // IEEE div + round-half-even = jnp
      q = fminf(fmaxf(q, -8.f), 7.f);
      o[i] = __float2bfloat16(q * scale);
    }
    bf16_t* dst = Ap + (size_t)row * KPAD + k0;
    ((uint4*)dst)[0] = ((uint4*)o)[0];
    ((uint4*)dst)[1] = ((uint4*)o)[1];
    if (tid < 32) Ap[(size_t)row * KPAD + 4128 + tid] = __float2bfloat16(0.f);

  } else if (bid < M_DIM + N_DIM) {        // ---- quant_w ----
    const int row = bid - M_DIM;
    const int k0  = tid * 16;
    const float* wr = w + (size_t)row * K_DIM + k0;

    float v[16];
#pragma unroll
    for (int i = 0; i < 4; ++i) {
      float4 wv = *(const float4*)(wr + i * 4);
      v[i*4+0] = wv.x; v[i*4+1] = wv.y; v[i*4+2] = wv.z; v[i*4+3] = wv.w;
    }
    float am = 0.f;
#pragma unroll
    for (int i = 0; i < 16; ++i) am = fmaxf(am, fabsf(v[i]));
    am = fmaxf(am, __shfl_xor(am, 1));
    am = fmaxf(am, __shfl_xor(am, 2));
    const float scale = fmaxf(am / QMAXF, 1e-8f);

    alignas(16) bf16_t o[16];
#pragma unroll
    for (int i = 0; i < 16; ++i) {
      float q = rintf(v[i] / scale);
      q = fminf(fmaxf(q, -8.f), 7.f);
      o[i] = __float2bfloat16(q * scale);
    }
    bf16_t* dst = Bp + (size_t)row * KPAD + k0;
    ((uint4*)dst)[0] = ((uint4*)o)[0];
    ((uint4*)dst)[1] = ((uint4*)o)[1];
    if (tid < 32) {
      Bp[(size_t)row * KPAD + 4096 + tid] = __float2bfloat16(lora_up[row * R_DIM + tid]);
    } else if (tid < 64) {
      Bp[(size_t)row * KPAD + 4096 + tid] = __float2bfloat16(0.f);
    }

  } else {                                 // ---- ldT ----
    const int k = (bid - M_DIM - N_DIM) * 256 + tid;
    float v[R_DIM];
#pragma unroll
    for (int i = 0; i < R_DIM / 4; ++i) {
      float4 a = *(const float4*)(ld + (size_t)k * R_DIM + i * 4);
      v[i*4+0] = a.x; v[i*4+1] = a.y; v[i*4+2] = a.z; v[i*4+3] = a.w;
    }
#pragma unroll
    for (int r = 0; r < R_DIM; ++r)
      ldT[(size_t)r * K_DIM + k] = __float2bfloat16(v[r]);
  }
}

// ---------------------------------------------------------------------------
// t = (x*smooth) @ lora_down  [M x 32] via MFMA -> Ap cols 4096..4127.
// ---------------------------------------------------------------------------
__global__ __launch_bounds__(256) void lora_mfma_kernel(
    const float* __restrict__ x, const float* __restrict__ smooth,
    const bf16_t* __restrict__ ldT, bf16_t* __restrict__ Ap) {
  const int tid  = threadIdx.x;
  const int w    = tid >> 6;
  const int lane = tid & 63;
  const int m0   = blockIdx.x * 32;

  const int mrow = m0 + (w >> 1) * 16 + (lane & 15);
  const int ncol = (w & 1) * 16 + (lane & 15);
  const float* xr = x + (size_t)mrow * K_DIM;
  const bf16_t* br = ldT + (size_t)ncol * K_DIM;

  f32x4 acc = {0.f, 0.f, 0.f, 0.f};
  union { bf16_t h[8]; bf16x8 v; } au;

  for (int k = 0; k < K_DIM; k += 32) {
    const int kf = k + (lane >> 4) * 8;
    float4 x0 = *(const float4*)(xr + kf);
    float4 x1 = *(const float4*)(xr + kf + 4);
    float4 s0 = *(const float4*)(smooth + kf);
    float4 s1 = *(const float4*)(smooth + kf + 4);
    au.h[0] = __float2bfloat16(x0.x * s0.x);
    au.h[1] = __float2bfloat16(x0.y * s0.y);
    au.h[2] = __float2bfloat16(x0.z * s0.z);
    au.h[3] = __float2bfloat16(x0.w * s0.w);
    au.h[4] = __float2bfloat16(x1.x * s1.x);
    au.h[5] = __float2bfloat16(x1.y * s1.y);
    au.h[6] = __float2bfloat16(x1.z * s1.z);
    au.h[7] = __float2bfloat16(x1.w * s1.w);
    bf16x8 bv = *(const bf16x8*)(br + kf);
    acc = __builtin_amdgcn_mfma_f32_16x16x32_bf16(au.v, bv, acc, 0, 0, 0);
  }

  const int orow = m0 + (w >> 1) * 16 + (lane >> 4) * 4;
  const int ocol = 4096 + ncol;
#pragma unroll
  for (int q = 0; q < 4; ++q)
    Ap[(size_t)(orow + q) * KPAD + ocol] = __float2bfloat16(acc[q]);
}

// ---------------------------------------------------------------------------
// 256x256x64 8-phase GEMM, A-fragments pipelined ONE PHASE ahead (aA/aB
// ping-pong), B-fragments single-set re-read once per ktile at P4's tail
// AFTER the MFMA cluster (in-order issue => WAR-safe; LDS data valid per the
// vmcnt(6) ring).  Each phase tail: barrier; lgkmcnt(0); issue next-quadrant
// A ds_reads; sched_barrier; MFMA.  The A-read latency hides under MFMA.
// Stage ring (unchanged): P1: A2(u+1)->buf^1 | P2: B1(u+2)->buf |
//   P3: B2(u+2)->buf | P4: A1(u+2)->buf + vmcnt(6)  (tail: vmcnt(0)).
// A quadrant-major LDS (lds_row = q*64 + wm*32 + r).  Swizzle: 16B granule
// ^= (row&7) on stage-source and ds_read (0-conflict, verified).
// ---------------------------------------------------------------------------
__global__ __launch_bounds__(512, 2) void gemm_kernel(
    const bf16_t* __restrict__ A, const bf16_t* __restrict__ B,
    const float* __restrict__ bias, float* __restrict__ C) {
  extern __shared__ __align__(16) bf16_t lds[];   // 65536 elems = 128 KiB

  // XCD-aware swizzle: nwg = 512, divisible by 8
  const int wg  = blockIdx.x;
  const int swz = (wg & 7) * 64 + (wg >> 3);
  const int bn  = swz & 15;    // 0..15
  const int bm  = swz >> 4;    // 0..31

  const int tid  = threadIdx.x;
  const int lane = tid & 63;
  const int wid  = tid >> 6;     // 0..7
  const int wm   = wid >> 2;     // 0..1
  const int wn   = wid & 3;      // 0..3

  const int lr = lane & 15;      // frag row within 16
  const int lg = lane >> 4;      // k-granule subindex 0..3
  const int l7 = lane & 7;
  const int gk0 = ((0 + lg) ^ l7) * 8;   // swizzled elem offset, k-half 0
  const int gk1 = ((4 + lg) ^ l7) * 8;   // k-half 1

  // staging geometry
  const int sr   = tid >> 3;                 // 0..63
  const int sl   = tid & 7;                  // granule slot
  const int gcol = (sl ^ (sr & 7)) * 8;      // inverse-swizzled source col
  const bf16_t* Abase = A + (size_t)(bm * 256 + ((sr >> 5) & 1) * 128 + (sr & 31)) * KPAD + gcol;
  const bf16_t* Bbase = B + (size_t)(bn * 256 + sr) * KPAD + gcol;
  bf16_t* ldsb = lds;

#define STAGE_A(buf, h, kt) do {                                               \
    stage16(Abase + (size_t)((h) * 2 + 0) * 32 * KPAD + (kt) * 64,             \
            ldsb + (buf) * 32768 + (h) * 8192 + 0 * 4096 + tid * 8);           \
    stage16(Abase + (size_t)((h) * 2 + 1) * 32 * KPAD + (kt) * 64,             \
            ldsb + (buf) * 32768 + (h) * 8192 + 1 * 4096 + tid * 8);           \
  } while (0)
#define STAGE_B(buf, h, kt) do {                                               \
    stage16(Bbase + (size_t)((h) * 128 + 0) * KPAD + (kt) * 64,                \
            ldsb + (buf) * 32768 + 16384 + (h) * 8192 + 0 * 4096 + tid * 8);   \
    stage16(Bbase + (size_t)((h) * 128 + 64) * KPAD + (kt) * 64,               \
            ldsb + (buf) * 32768 + 16384 + (h) * 8192 + 1 * 4096 + tid * 8);   \
  } while (0)

  f32x4  acc[8][4] = {};
  bf16x8 aA[2][2];   // A-frag ping (quadrants 0,2)
  bf16x8 aB[2][2];   // A-frag pong (quadrants 1,3)
  bf16x8 bF[4][2];   // B-frags, one set, reloaded per ktile

#define LOAD_A(DST, q, cb) do {                                                \
    const bf16_t* pa_ = ldsb + (cb) * 32768 + ((q) * 64 + wm * 32 + lr) * 64;  \
    DST[0][0] = *(const bf16x8*)(pa_ + gk0);                                   \
    DST[0][1] = *(const bf16x8*)(pa_ + gk1);                                   \
    DST[1][0] = *(const bf16x8*)(pa_ + 1024 + gk0);                            \
    DST[1][1] = *(const bf16x8*)(pa_ + 1024 + gk1);                            \
  } while (0)
#define LOAD_BN(nbuf) do {                                                     \
    _Pragma("unroll")                                                          \
    for (int j = 0; j < 4; ++j) {                                              \
      const bf16_t* pb_ = ldsb + (nbuf) * 32768 + 16384 + (wn * 64 + j * 16 + lr) * 64; \
      bF[j][0] = *(const bf16x8*)(pb_ + gk0);                                  \
      bF[j][1] = *(const bf16x8*)(pb_ + gk1);                                  \
    }                                                                          \
  } while (0)
#define MFMA_Q(q, AARR) do {                                                   \
    _Pragma("unroll")                                                          \
    for (int i = 0; i < 2; ++i)                                                \
      _Pragma("unroll")                                                        \
      for (int j = 0; j < 4; ++j) {                                            \
        acc[(q)*2+i][j] = __builtin_amdgcn_mfma_f32_16x16x32_bf16(             \
            AARR[i][0], bF[j][0], acc[(q)*2+i][j], 0, 0, 0);                   \
        acc[(q)*2+i][j] = __builtin_amdgcn_mfma_f32_16x16x32_bf16(             \
            AARR[i][1], bF[j][1], acc[(q)*2+i][j], 0, 0, 0);                   \
      }                                                                        \
  } while (0)

#define KTILE(u, cur) do {                                                     \
    /* ---- P1 ---- */                                                         \
    if ((u) + 1 < NT) STAGE_A((cur) ^ 1, 1, (u) + 1);                          \
    __builtin_amdgcn_s_barrier();                                              \
    asm volatile("s_waitcnt lgkmcnt(0)" ::: "memory");                         \
    __builtin_amdgcn_sched_barrier(0);                                         \
    LOAD_A(aB, 1, cur);                                                        \
    __builtin_amdgcn_sched_barrier(0);                                         \
    __builtin_amdgcn_s_setprio(1);                                             \
    MFMA_Q(0, aA);                                                             \
    __builtin_amdgcn_s_setprio(0);                                             \
    __builtin_amdgcn_s_barrier();                                              \
    /* ---- P2 ---- */                                                         \
    if ((u) + 2 < NT) STAGE_B(cur, 0, (u) + 2);                                \
    __builtin_amdgcn_s_barrier();                                              \
    asm volatile("s_waitcnt lgkmcnt(0)" ::: "memory");                         \
    __builtin_amdgcn_sched_barrier(0);                                         \
    LOAD_A(aA, 2, cur);                                                        \
    __builtin_amdgcn_sched_barrier(0);                                         \
    __builtin_amdgcn_s_setprio(1);                                             \
    MFMA_Q(1, aB);                                                             \
    __builtin_amdgcn_s_setprio(0);                                             \
    __builtin_amdgcn_s_barrier();                                              \
    /* ---- P3 ---- */                                                         \
    if ((u) + 2 < NT) STAGE_B(cur, 1, (u) + 2);                                \
    __builtin_amdgcn_s_barrier();                                              \
    asm volatile("s_waitcnt lgkmcnt(0)" ::: "memory");                         \
    __builtin_amdgcn_sched_barrier(0);                                         \
    LOAD_A(aB, 3, cur);                                                        \
    __builtin_amdgcn_sched_barrier(0);                                         \
    __builtin_amdgcn_s_setprio(1);                                             \
    MFMA_Q(2, aA);                                                             \
    __builtin_amdgcn_s_setprio(0);                                             \
    __builtin_amdgcn_s_barrier();                                              \
    /* ---- P4 ---- */                                                         \
    if ((u) + 2 < NT) {                                                        \
      STAGE_A(cur, 0, (u) + 2);                                                \
      asm volatile("s_waitcnt vmcnt(6)" ::: "memory");                         \
    } else {                                                                   \
      asm volatile("s_waitcnt vmcnt(0)" ::: "memory");                         \
    }                                                                          \
    __builtin_amdgcn_s_barrier();                                              \
    asm volatile("s_waitcnt lgkmcnt(0)" ::: "memory");                         \
    __builtin_amdgcn_sched_barrier(0);                                         \
    if ((u) + 1 < NT) LOAD_A(aA, 0, (cur) ^ 1);                                \
    __builtin_amdgcn_sched_barrier(0);                                         \
    __builtin_amdgcn_s_setprio(1);                                             \
    MFMA_Q(3, aB);                                                             \
    __builtin_amdgcn_s_setprio(0);                                             \
    __builtin_amdgcn_sched_barrier(0);                                         \
    if ((u) + 1 < NT) LOAD_BN((cur) ^ 1);                                      \
    __builtin_amdgcn_s_barrier();                                              \
  } while (0)

  // ---- prologue: stage ktile0 fully + ktile1's B1,B2,A1; wait ktile0;
  //      preload B(0) and A-q0(0) fragment registers ----
  STAGE_B(0, 0, 0); STAGE_B(0, 1, 0); STAGE_A(0, 0, 0); STAGE_A(0, 1, 0);
  STAGE_B(1, 0, 1); STAGE_B(1, 1, 1); STAGE_A(1, 0, 1);
  asm volatile("s_waitcnt vmcnt(6)" ::: "memory");
  __builtin_amdgcn_s_barrier();
  LOAD_BN(0);
  LOAD_A(aA, 0, 0);

  for (int base = 0; base < 64; base += 2) {
    KTILE(base,     0);
    KTILE(base + 1, 1);
  }
  KTILE(64, 0);

  // ---- epilogue: C/D layout col = lane&15, row = (lane>>4)*4 + e ----
  const int colb = bn * 256 + wn * 64 + lr;
  const int rowb = bm * 256 + wm * 128 + lg * 4;
#pragma unroll
  for (int j = 0; j < 4; ++j) {
    const int gc = colb + j * 16;
    const float bv = bias[gc];
#pragma unroll
    for (int q = 0; q < 4; ++q)
#pragma unroll
      for (int i = 0; i < 2; ++i) {
        const int gr = rowb + q * 32 + i * 16;
#pragma unroll
        for (int e = 0; e < 4; ++e)
          C[(size_t)(gr + e) * N_DIM + gc] = acc[q * 2 + i][j][e] + bv;
      }
  }
#undef STAGE_A
#undef STAGE_B
#undef LOAD_A
#undef LOAD_BN
#undef MFMA_Q
#undef KTILE
}

// ---------------------------------------------------------------------------
extern "C" void kernel_launch(void* const* d_in, const int* in_sizes, int n_in,
                              void* d_out, int out_size, void* d_ws, size_t ws_size,
                              hipStream_t stream) {
  const float* x         = (const float*)d_in[0];
  const float* w_res     = (const float*)d_in[1];
  const float* lora_down = (const float*)d_in[2];
  const float* lora_up   = (const float*)d_in[3];
  const float* smooth    = (const float*)d_in[4];
  const float* b         = (const float*)d_in[5];
  float* out = (float*)d_out;

  // workspace: Ap [M][KPAD] bf16 (68.2 MB), Bp [N][KPAD] bf16 (34.1 MB),
  // ldT [R][K] bf16 (256 KB)
  bf16_t* Ap  = (bf16_t*)d_ws;
  bf16_t* Bp  = Ap + (size_t)M_DIM * KPAD;
  bf16_t* ldT = Bp + (size_t)N_DIM * KPAD;

  // allow 128 KiB dynamic LDS (idempotent, host-side, capture-safe)
  hipFuncSetAttribute((const void*)gemm_kernel,
                      hipFuncAttributeMaxDynamicSharedMemorySize, 131072);

  prep_kernel<<<M_DIM + N_DIM + K_DIM / 256, 256, 0, stream>>>(
      x, smooth, w_res, lora_up, lora_down, Ap, Bp, ldT);
  lora_mfma_kernel<<<M_DIM / 32, 256, 0, stream>>>(x, smooth, ldT, Ap);
  gemm_kernel<<<(M_DIM / 256) * (N_DIM / 256), 512, 131072, stream>>>(Ap, Bp, b, out);
}